// Round 3
// baseline (1762.487 us; speedup 1.0000x reference)
//
#include <hip/hip_runtime.h>

#define BB 2
#define NN 32768
#define EN 32768   // edges per batch

typedef float4 f4;

// ---------------------------------------------------------------------------
// float4 helpers (explicit, no reliance on vector operator overloads)
// ---------------------------------------------------------------------------
__device__ __forceinline__ f4 ffma(float a, f4 w, f4 c) {
    c.x = fmaf(a, w.x, c.x); c.y = fmaf(a, w.y, c.y);
    c.z = fmaf(a, w.z, c.z); c.w = fmaf(a, w.w, c.w);
    return c;
}
__device__ __forceinline__ f4 reluadd4(f4 n, f4 b) {
    f4 r;
    r.x = fmaxf(n.x + b.x, 0.f); r.y = fmaxf(n.y + b.y, 0.f);
    r.z = fmaxf(n.z + b.z, 0.f); r.w = fmaxf(n.w + b.w, 0.f);
    return r;
}
__device__ __forceinline__ f4 zero4() { f4 r; r.x = r.y = r.z = r.w = 0.f; return r; }

// ---------------------------------------------------------------------------
// LayerNorm over 32 values held in 8 named float4s (per-lane)
// ---------------------------------------------------------------------------
__device__ __forceinline__ void ln32(f4& h0, f4& h1, f4& h2, f4& h3,
                                     f4& h4, f4& h5, f4& h6, f4& h7,
                                     const float* __restrict__ g,
                                     const float* __restrict__ b)
{
    float m = h0.x + h0.y + h0.z + h0.w + h1.x + h1.y + h1.z + h1.w
            + h2.x + h2.y + h2.z + h2.w + h3.x + h3.y + h3.z + h3.w
            + h4.x + h4.y + h4.z + h4.w + h5.x + h5.y + h5.z + h5.w
            + h6.x + h6.y + h6.z + h6.w + h7.x + h7.y + h7.z + h7.w;
    m *= (1.f / 32.f);
    float v = 0.f;
#define LNV(H) { float d; d = H.x - m; v = fmaf(d, d, v); d = H.y - m; v = fmaf(d, d, v); \
                 d = H.z - m; v = fmaf(d, d, v); d = H.w - m; v = fmaf(d, d, v); }
    LNV(h0) LNV(h1) LNV(h2) LNV(h3) LNV(h4) LNV(h5) LNV(h6) LNV(h7)
#undef LNV
    v *= (1.f / 32.f);
    const float r = rsqrtf(v + 1e-5f);
    const f4* __restrict__ g4 = reinterpret_cast<const f4*>(g);
    const f4* __restrict__ b4 = reinterpret_cast<const f4*>(b);
#define LNA(H, I) { f4 gg = g4[I], bb = b4[I]; \
    H.x = fmaf((H.x - m) * r, gg.x, bb.x); H.y = fmaf((H.y - m) * r, gg.y, bb.y); \
    H.z = fmaf((H.z - m) * r, gg.z, bb.z); H.w = fmaf((H.w - m) * r, gg.w, bb.w); }
    LNA(h0,0) LNA(h1,1) LNA(h2,2) LNA(h3,3) LNA(h4,4) LNA(h5,5) LNA(h6,6) LNA(h7,7)
#undef LNA
}

// ---------------------------------------------------------------------------
// named-register row buffers
// ---------------------------------------------------------------------------
#define DECL8(P) f4 P##0, P##1, P##2, P##3, P##4, P##5, P##6, P##7
#define LOAD8(P, PTR) { const f4* _q = reinterpret_cast<const f4*>(PTR); \
    P##0 = _q[0]; P##1 = _q[1]; P##2 = _q[2]; P##3 = _q[3]; \
    P##4 = _q[4]; P##5 = _q[5]; P##6 = _q[6]; P##7 = _q[7]; }
#define FMA8(A, W, N) { N##0 = ffma(A, W##0, N##0); N##1 = ffma(A, W##1, N##1); \
    N##2 = ffma(A, W##2, N##2); N##3 = ffma(A, W##3, N##3); \
    N##4 = ffma(A, W##4, N##4); N##5 = ffma(A, W##5, N##5); \
    N##6 = ffma(A, W##6, N##6); N##7 = ffma(A, W##7, N##7); }

// Hidden stack: 32 layers of 32->32, with a 3-buffer rotating weight-row
// pipeline (row k in use, k+1 ready, k+2 in flight -> ~128cyc latency cover).
// LN (if any) runs at layer top (params lng[l]); final LN after the loop.
template<bool HAS_LN>
__device__ __forceinline__ void hidden32(
    f4& h0, f4& h1, f4& h2, f4& h3, f4& h4, f4& h5, f4& h6, f4& h7,
    const float* __restrict__ Wh, const float* __restrict__ bh,
    const float* __restrict__ lng, const float* __restrict__ lnb)
{
    #pragma unroll 1
    for (int l = 0; l < 32; ++l) {
        const float* __restrict__ Wl = Wh + l * 1024;
        DECL8(wA); DECL8(wB); DECL8(wC);
        LOAD8(wA, Wl);            // row 0
        LOAD8(wB, Wl + 32);       // row 1
        if (HAS_LN) ln32(h0,h1,h2,h3,h4,h5,h6,h7, lng + l*32, lnb + l*32);
        f4 n0=zero4(), n1=zero4(), n2=zero4(), n3=zero4();
        f4 n4=zero4(), n5=zero4(), n6=zero4(), n7=zero4();
#define HS(BUSE, BLD, KN, AV) { if ((KN) < 32) LOAD8(BLD, Wl + (KN)*32); FMA8(AV, BUSE, n) }
        HS(wA,wC, 2, h0.x) HS(wB,wA, 3, h0.y) HS(wC,wB, 4, h0.z) HS(wA,wC, 5, h0.w)
        HS(wB,wA, 6, h1.x) HS(wC,wB, 7, h1.y) HS(wA,wC, 8, h1.z) HS(wB,wA, 9, h1.w)
        HS(wC,wB,10, h2.x) HS(wA,wC,11, h2.y) HS(wB,wA,12, h2.z) HS(wC,wB,13, h2.w)
        HS(wA,wC,14, h3.x) HS(wB,wA,15, h3.y) HS(wC,wB,16, h3.z) HS(wA,wC,17, h3.w)
        HS(wB,wA,18, h4.x) HS(wC,wB,19, h4.y) HS(wA,wC,20, h4.z) HS(wB,wA,21, h4.w)
        HS(wC,wB,22, h5.x) HS(wA,wC,23, h5.y) HS(wB,wA,24, h5.z) HS(wC,wB,25, h5.w)
        HS(wA,wC,26, h6.x) HS(wB,wA,27, h6.y) HS(wC,wB,28, h6.z) HS(wA,wC,29, h6.w)
        HS(wB,wA,30, h7.x) HS(wC,wB,31, h7.y) HS(wA,wC,32, h7.z) HS(wB,wA,33, h7.w)
#undef HS
        const f4* __restrict__ bl4 = reinterpret_cast<const f4*>(bh + l*32);
        h0 = reluadd4(n0, bl4[0]); h1 = reluadd4(n1, bl4[1]);
        h2 = reluadd4(n2, bl4[2]); h3 = reluadd4(n3, bl4[3]);
        h4 = reluadd4(n4, bl4[4]); h5 = reluadd4(n5, bl4[5]);
        h6 = reluadd4(n6, bl4[6]); h7 = reluadd4(n7, bl4[7]);
    }
    if (HAS_LN) ln32(h0,h1,h2,h3,h4,h5,h6,h7, lng + 32*32, lnb + 32*32);
}

// Input layer: din -> 32 (small; simple unrolled stream)
template<int DIN>
__device__ __forceinline__ void in_layer(
    const float* x, const float* __restrict__ Win, const float* __restrict__ bin,
    f4& h0, f4& h1, f4& h2, f4& h3, f4& h4, f4& h5, f4& h6, f4& h7)
{
    f4 n0=zero4(), n1=zero4(), n2=zero4(), n3=zero4();
    f4 n4=zero4(), n5=zero4(), n6=zero4(), n7=zero4();
    #pragma unroll
    for (int k = 0; k < DIN; ++k) {
        const f4* __restrict__ r = reinterpret_cast<const f4*>(Win + k*32);
        const float a = x[k];
        n0 = ffma(a, r[0], n0); n1 = ffma(a, r[1], n1);
        n2 = ffma(a, r[2], n2); n3 = ffma(a, r[3], n3);
        n4 = ffma(a, r[4], n4); n5 = ffma(a, r[5], n5);
        n6 = ffma(a, r[6], n6); n7 = ffma(a, r[7], n7);
    }
    const f4* __restrict__ b4 = reinterpret_cast<const f4*>(bin);
    h0 = reluadd4(n0, b4[0]); h1 = reluadd4(n1, b4[1]);
    h2 = reluadd4(n2, b4[2]); h3 = reluadd4(n3, b4[3]);
    h4 = reluadd4(n4, b4[4]); h5 = reluadd4(n5, b4[5]);
    h6 = reluadd4(n6, b4[6]); h7 = reluadd4(n7, b4[7]);
}

// Output layer 32 -> 16 (relu), into 4 named f4 accumulators
#define OUT16(Wout, bout, O0,O1,O2,O3) { \
    O0 = zero4(); O1 = zero4(); O2 = zero4(); O3 = zero4(); \
    const float* _wo = (Wout); \
    _Pragma("unroll") \
    for (int _kk = 0; _kk < 8; ++_kk) { \
        f4 _a = (_kk==0)?h0:(_kk==1)?h1:(_kk==2)?h2:(_kk==3)?h3:(_kk==4)?h4:(_kk==5)?h5:(_kk==6)?h6:h7; \
        const f4* _r0 = reinterpret_cast<const f4*>(_wo + (_kk*4+0)*16); \
        const f4* _r1 = reinterpret_cast<const f4*>(_wo + (_kk*4+1)*16); \
        const f4* _r2 = reinterpret_cast<const f4*>(_wo + (_kk*4+2)*16); \
        const f4* _r3 = reinterpret_cast<const f4*>(_wo + (_kk*4+3)*16); \
        O0 = ffma(_a.x, _r0[0], O0); O1 = ffma(_a.x, _r0[1], O1); O2 = ffma(_a.x, _r0[2], O2); O3 = ffma(_a.x, _r0[3], O3); \
        O0 = ffma(_a.y, _r1[0], O0); O1 = ffma(_a.y, _r1[1], O1); O2 = ffma(_a.y, _r1[2], O2); O3 = ffma(_a.y, _r1[3], O3); \
        O0 = ffma(_a.z, _r2[0], O0); O1 = ffma(_a.z, _r2[1], O1); O2 = ffma(_a.z, _r2[2], O2); O3 = ffma(_a.z, _r2[3], O3); \
        O0 = ffma(_a.w, _r3[0], O0); O1 = ffma(_a.w, _r3[1], O1); O2 = ffma(_a.w, _r3[2], O2); O3 = ffma(_a.w, _r3[3], O3); \
    } \
    const f4* _b4 = reinterpret_cast<const f4*>(bout); \
    O0 = reluadd4(O0, _b4[0]); O1 = reluadd4(O1, _b4[1]); \
    O2 = reluadd4(O2, _b4[2]); O3 = reluadd4(O3, _b4[3]); }

#define DECLH f4 h0,h1,h2,h3,h4,h5,h6,h7

// ---------------------------------------------------------------------------
// kernels  (grid = 256 blocks x 256 thr = 1 block/CU; occupancy is
// grid-limited at 1 wave/SIMD, so allow max registers)
// ---------------------------------------------------------------------------
__global__ __launch_bounds__(256, 1) void node_encode_kernel(
    const float* __restrict__ nodes, const float* __restrict__ gvec,
    const float* __restrict__ Win,  const float* __restrict__ bin,
    const float* __restrict__ Wh,   const float* __restrict__ bh,
    const float* __restrict__ Wout, const float* __restrict__ bout,
    float* __restrict__ ve)
{
    const int idx = blockIdx.x * blockDim.x + threadIdx.x;
    if (idx >= BB * NN) return;
    const int b = idx >> 15;
    float x[7];
    #pragma unroll
    for (int i = 0; i < 6; ++i) x[i] = nodes[(size_t)idx * 6 + i];
    x[6] = gvec[b];
    DECLH;
    in_layer<7>(x, Win, bin, h0,h1,h2,h3,h4,h5,h6,h7);
    hidden32<false>(h0,h1,h2,h3,h4,h5,h6,h7, Wh, bh, nullptr, nullptr);
    f4 o0,o1,o2,o3;
    OUT16(Wout, bout, o0,o1,o2,o3);
    f4* dst = reinterpret_cast<f4*>(ve + (size_t)idx * 16);
    dst[0]=o0; dst[1]=o1; dst[2]=o2; dst[3]=o3;
}

__global__ __launch_bounds__(256, 1) void edge_encode_kernel(
    const float* __restrict__ nodes, const float* __restrict__ edges,
    const int* __restrict__ senders, const int* __restrict__ receivers,
    const float* __restrict__ Win,  const float* __restrict__ bin,
    const float* __restrict__ Wh,   const float* __restrict__ bh,
    const float* __restrict__ Wout, const float* __restrict__ bout,
    float* __restrict__ ee)
{
    const int idx = blockIdx.x * blockDim.x + threadIdx.x;
    if (idx >= BB * EN) return;
    const int b = idx >> 15;
    const int s = senders[idx];
    const int r = receivers[idx];
    const float* ps = nodes + ((size_t)b * NN + s) * 6;
    const float* pr = nodes + ((size_t)b * NN + r) * 6;
    float rel0 = ps[0] - pr[0];
    float rel1 = ps[1] - pr[1];
    float rel2 = ps[2] - pr[2];
    float nrm = sqrtf(rel0*rel0 + rel1*rel1 + rel2*rel2);
    float x[5] = { edges[idx], rel0, rel1, rel2, nrm };
    DECLH;
    in_layer<5>(x, Win, bin, h0,h1,h2,h3,h4,h5,h6,h7);
    hidden32<false>(h0,h1,h2,h3,h4,h5,h6,h7, Wh, bh, nullptr, nullptr);
    f4 o0,o1,o2,o3;
    OUT16(Wout, bout, o0,o1,o2,o3);
    f4* dst = reinterpret_cast<f4*>(ee + (size_t)idx * 16);
    dst[0]=o0; dst[1]=o1; dst[2]=o2; dst[3]=o3;
}

__global__ __launch_bounds__(256, 1) void edge_update_kernel(
    const float* __restrict__ gvec,
    const int* __restrict__ senders, const int* __restrict__ receivers,
    const float* __restrict__ ve, float* __restrict__ ee, float* __restrict__ agg,
    const float* __restrict__ Win,  const float* __restrict__ bin,
    const float* __restrict__ Wh,   const float* __restrict__ bh,
    const float* __restrict__ Wout, const float* __restrict__ bout,
    const float* __restrict__ lng,  const float* __restrict__ lnb)
{
    const int idx = blockIdx.x * blockDim.x + threadIdx.x;
    if (idx >= BB * EN) return;
    const int b = idx >> 15;
    const int s = senders[idx];
    const int r = receivers[idx];
    float x[49];
    {
        const f4* p0 = reinterpret_cast<const f4*>(ee + (size_t)idx * 16);
        const f4* p1 = reinterpret_cast<const f4*>(ve + ((size_t)b * NN + s) * 16);
        const f4* p2 = reinterpret_cast<const f4*>(ve + ((size_t)b * NN + r) * 16);
        #pragma unroll
        for (int i = 0; i < 4; ++i) { f4 v = p0[i]; x[4*i]=v.x; x[4*i+1]=v.y; x[4*i+2]=v.z; x[4*i+3]=v.w; }
        #pragma unroll
        for (int i = 0; i < 4; ++i) { f4 v = p1[i]; x[16+4*i]=v.x; x[16+4*i+1]=v.y; x[16+4*i+2]=v.z; x[16+4*i+3]=v.w; }
        #pragma unroll
        for (int i = 0; i < 4; ++i) { f4 v = p2[i]; x[32+4*i]=v.x; x[32+4*i+1]=v.y; x[32+4*i+2]=v.z; x[32+4*i+3]=v.w; }
        x[48] = gvec[b];
    }
    DECLH;
    in_layer<49>(x, Win, bin, h0,h1,h2,h3,h4,h5,h6,h7);
    hidden32<true>(h0,h1,h2,h3,h4,h5,h6,h7, Wh, bh, lng, lnb);
    f4 o0,o1,o2,o3;
    OUT16(Wout, bout, o0,o1,o2,o3);
    f4* dst = reinterpret_cast<f4*>(ee + (size_t)idx * 16);
    dst[0]=o0; dst[1]=o1; dst[2]=o2; dst[3]=o3;
    float* ap = agg + ((size_t)b * NN + r) * 16;
    atomicAdd(ap+ 0, o0.x); atomicAdd(ap+ 1, o0.y); atomicAdd(ap+ 2, o0.z); atomicAdd(ap+ 3, o0.w);
    atomicAdd(ap+ 4, o1.x); atomicAdd(ap+ 5, o1.y); atomicAdd(ap+ 6, o1.z); atomicAdd(ap+ 7, o1.w);
    atomicAdd(ap+ 8, o2.x); atomicAdd(ap+ 9, o2.y); atomicAdd(ap+10, o2.z); atomicAdd(ap+11, o2.w);
    atomicAdd(ap+12, o3.x); atomicAdd(ap+13, o3.y); atomicAdd(ap+14, o3.z); atomicAdd(ap+15, o3.w);
}

__global__ __launch_bounds__(256, 1) void node_update_kernel(
    const float* __restrict__ gvec,
    const float* __restrict__ agg, float* __restrict__ ve,
    const float* __restrict__ Win,  const float* __restrict__ bin,
    const float* __restrict__ Wh,   const float* __restrict__ bh,
    const float* __restrict__ Wout, const float* __restrict__ bout,
    const float* __restrict__ lng,  const float* __restrict__ lnb)
{
    const int idx = blockIdx.x * blockDim.x + threadIdx.x;
    if (idx >= BB * NN) return;
    const int b = idx >> 15;
    float x[33];
    {
        const f4* p0 = reinterpret_cast<const f4*>(agg + (size_t)idx * 16);
        const f4* p1 = reinterpret_cast<const f4*>(ve  + (size_t)idx * 16);
        #pragma unroll
        for (int i = 0; i < 4; ++i) { f4 v = p0[i]; x[4*i]=v.x; x[4*i+1]=v.y; x[4*i+2]=v.z; x[4*i+3]=v.w; }
        #pragma unroll
        for (int i = 0; i < 4; ++i) { f4 v = p1[i]; x[16+4*i]=v.x; x[16+4*i+1]=v.y; x[16+4*i+2]=v.z; x[16+4*i+3]=v.w; }
        x[32] = gvec[b];
    }
    DECLH;
    in_layer<33>(x, Win, bin, h0,h1,h2,h3,h4,h5,h6,h7);
    hidden32<true>(h0,h1,h2,h3,h4,h5,h6,h7, Wh, bh, lng, lnb);
    f4 o0,o1,o2,o3;
    OUT16(Wout, bout, o0,o1,o2,o3);
    f4* dst = reinterpret_cast<f4*>(ve + (size_t)idx * 16);
    dst[0]=o0; dst[1]=o1; dst[2]=o2; dst[3]=o3;
}

__global__ __launch_bounds__(256, 1) void decode_kernel(
    const float* __restrict__ ve,
    const float* __restrict__ Win,  const float* __restrict__ bin,
    const float* __restrict__ Wh,   const float* __restrict__ bh,
    const float* __restrict__ Wout, const float* __restrict__ bout,
    float* __restrict__ out)
{
    const int idx = blockIdx.x * blockDim.x + threadIdx.x;
    if (idx >= BB * NN) return;
    float x[16];
    {
        const f4* p0 = reinterpret_cast<const f4*>(ve + (size_t)idx * 16);
        #pragma unroll
        for (int i = 0; i < 4; ++i) { f4 v = p0[i]; x[4*i]=v.x; x[4*i+1]=v.y; x[4*i+2]=v.z; x[4*i+3]=v.w; }
    }
    DECLH;
    in_layer<16>(x, Win, bin, h0,h1,h2,h3,h4,h5,h6,h7);
    hidden32<false>(h0,h1,h2,h3,h4,h5,h6,h7, Wh, bh, nullptr, nullptr);
    // 32 -> 3 output
    float o0 = 0.f, o1 = 0.f, o2 = 0.f;
    #pragma unroll
    for (int kk = 0; kk < 8; ++kk) {
        f4 a = (kk==0)?h0:(kk==1)?h1:(kk==2)?h2:(kk==3)?h3:(kk==4)?h4:(kk==5)?h5:(kk==6)?h6:h7;
        const float* r0 = Wout + (kk*4+0)*3;
        const float* r1 = Wout + (kk*4+1)*3;
        const float* r2 = Wout + (kk*4+2)*3;
        const float* r3 = Wout + (kk*4+3)*3;
        o0 = fmaf(a.x, r0[0], o0); o1 = fmaf(a.x, r0[1], o1); o2 = fmaf(a.x, r0[2], o2);
        o0 = fmaf(a.y, r1[0], o0); o1 = fmaf(a.y, r1[1], o1); o2 = fmaf(a.y, r1[2], o2);
        o0 = fmaf(a.z, r2[0], o0); o1 = fmaf(a.z, r2[1], o1); o2 = fmaf(a.z, r2[2], o2);
        o0 = fmaf(a.w, r3[0], o0); o1 = fmaf(a.w, r3[1], o1); o2 = fmaf(a.w, r3[2], o2);
    }
    out[(size_t)idx*3 + 0] = fmaxf(o0 + bout[0], 0.f);
    out[(size_t)idx*3 + 1] = fmaxf(o1 + bout[1], 0.f);
    out[(size_t)idx*3 + 2] = fmaxf(o2 + bout[2], 0.f);
}

// ---------------------------------------------------------------------------
// launch
// ---------------------------------------------------------------------------
extern "C" void kernel_launch(void* const* d_in, const int* in_sizes, int n_in,
                              void* d_out, int out_size, void* d_ws, size_t ws_size,
                              hipStream_t stream)
{
    const float* nodes     = (const float*)d_in[0];
    const float* edges     = (const float*)d_in[1];
    const float* gvec      = (const float*)d_in[2];
    const int*   senders   = (const int*)  d_in[3];
    const int*   receivers = (const int*)  d_in[4];

    const float* ne_Win  = (const float*)d_in[5];
    const float* ne_bin  = (const float*)d_in[6];
    const float* ne_Wh   = (const float*)d_in[7];
    const float* ne_bh   = (const float*)d_in[8];
    const float* ne_Wout = (const float*)d_in[9];
    const float* ne_bout = (const float*)d_in[10];

    const float* ed_Win  = (const float*)d_in[11];
    const float* ed_bin  = (const float*)d_in[12];
    const float* ed_Wh   = (const float*)d_in[13];
    const float* ed_bh   = (const float*)d_in[14];
    const float* ed_Wout = (const float*)d_in[15];
    const float* ed_bout = (const float*)d_in[16];

    const float* pe_Win  = (const float*)d_in[17];
    const float* pe_bin  = (const float*)d_in[18];
    const float* pe_Wh   = (const float*)d_in[19];
    const float* pe_bh   = (const float*)d_in[20];
    const float* pe_Wout = (const float*)d_in[21];
    const float* pe_bout = (const float*)d_in[22];
    const float* pe_lng  = (const float*)d_in[23];
    const float* pe_lnb  = (const float*)d_in[24];

    const float* pv_Win  = (const float*)d_in[25];
    const float* pv_bin  = (const float*)d_in[26];
    const float* pv_Wh   = (const float*)d_in[27];
    const float* pv_bh   = (const float*)d_in[28];
    const float* pv_Wout = (const float*)d_in[29];
    const float* pv_bout = (const float*)d_in[30];
    const float* pv_lng  = (const float*)d_in[31];
    const float* pv_lnb  = (const float*)d_in[32];

    const float* de_Win  = (const float*)d_in[33];
    const float* de_bin  = (const float*)d_in[34];
    const float* de_Wh   = (const float*)d_in[35];
    const float* de_bh   = (const float*)d_in[36];
    const float* de_Wout = (const float*)d_in[37];
    const float* de_bout = (const float*)d_in[38];

    // workspace layout (floats): ve | ee | agg  (1 Mi floats = 4 MB each)
    float* ve  = (float*)d_ws;
    float* ee  = ve + (size_t)BB * NN * 16;
    float* agg = ee + (size_t)BB * EN * 16;

    const dim3 blk(256);
    const dim3 grd((BB * NN + 255) / 256);

    node_encode_kernel<<<grd, blk, 0, stream>>>(nodes, gvec,
        ne_Win, ne_bin, ne_Wh, ne_bh, ne_Wout, ne_bout, ve);

    edge_encode_kernel<<<grd, blk, 0, stream>>>(nodes, edges, senders, receivers,
        ed_Win, ed_bin, ed_Wh, ed_bh, ed_Wout, ed_bout, ee);

    for (int step = 0; step < 2; ++step) {
        hipMemsetAsync(agg, 0, (size_t)BB * NN * 16 * sizeof(float), stream);
        edge_update_kernel<<<grd, blk, 0, stream>>>(gvec, senders, receivers,
            ve, ee, agg,
            pe_Win, pe_bin, pe_Wh, pe_bh, pe_Wout, pe_bout, pe_lng, pe_lnb);
        node_update_kernel<<<grd, blk, 0, stream>>>(gvec, agg, ve,
            pv_Win, pv_bin, pv_Wh, pv_bh, pv_Wout, pv_bout, pv_lng, pv_lnb);
    }

    decode_kernel<<<grd, blk, 0, stream>>>(ve,
        de_Win, de_bin, de_Wh, de_bh, de_Wout, de_bout, (float*)d_out);
}

// Round 4
// 397.313 us; speedup vs baseline: 4.4360x; 4.4360x over previous
//
#include <hip/hip_runtime.h>

#define BB 2
#define NN 32768
#define EN 32768

typedef unsigned int u32;
typedef __attribute__((ext_vector_type(8))) short bf16x8;
typedef __attribute__((ext_vector_type(4))) float f32x4;

union U4 { uint4 u; bf16x8 h; };

// round-to-nearest-even f32->bf16, packed pair (lo in low 16 bits)
__device__ __forceinline__ u32 pk2(float lo, float hi) {
    u32 a = __builtin_bit_cast(u32, lo);
    u32 b = __builtin_bit_cast(u32, hi);
    a += 0x7FFFu + ((a >> 16) & 1u);
    b += 0x7FFFu + ((b >> 16) & 1u);
    return (a >> 16) | (b & 0xFFFF0000u);
}

// ---------------------------------------------------------------------------
// Per-layer epilogue. D0/D1 = MFMA outputs for n-halves [0,16) and [16,32).
// C-layout: value r of half h belongs to element m=q*4+r, feature n+16h.
// Round-trip through LDS X (f32, row stride 36) to re-distribute to
// owner-lanes: lane (n,q) owns element n, features q*8..q*8+7. Owner applies
// bias+relu (+LN with 2 shfl_xor cross-owner reductions), packs bf16 pairs,
// writes A-layout row to LDS Y (u32 dwords, row stride 36).
// Wave-synchronous: no barriers needed (all traffic is wave-private).
// ---------------------------------------------------------------------------
template<bool LN>
__device__ __forceinline__ void epilogue(
    f32x4 D0, f32x4 D1,
    const float* __restrict__ bias,
    const float* __restrict__ lg,
    const float* __restrict__ lb,
    float* X, u32* Y, int n, int q)
{
    #pragma unroll
    for (int r = 0; r < 4; ++r) X[(q*4+r)*36 + n]      = D0[r];
    #pragma unroll
    for (int r = 0; r < 4; ++r) X[(q*4+r)*36 + 16 + n] = D1[r];
    const float* xr = X + n*36 + q*8;
    float4 xa = *(const float4*)xr;
    float4 xb = *(const float4*)(xr + 4);
    float4 ba = *(const float4*)(bias + q*8);
    float4 bb = *(const float4*)(bias + q*8 + 4);
    float y0 = fmaxf(xa.x+ba.x, 0.f), y1 = fmaxf(xa.y+ba.y, 0.f);
    float y2 = fmaxf(xa.z+ba.z, 0.f), y3 = fmaxf(xa.w+ba.w, 0.f);
    float y4 = fmaxf(xb.x+bb.x, 0.f), y5 = fmaxf(xb.y+bb.y, 0.f);
    float y6 = fmaxf(xb.z+bb.z, 0.f), y7 = fmaxf(xb.w+bb.w, 0.f);
    if (LN) {
        float s = ((y0+y1)+(y2+y3)) + ((y4+y5)+(y6+y7));
        s += __shfl_xor(s, 16);
        s += __shfl_xor(s, 32);
        float mu = s * (1.f/32.f);
        float d, v = 0.f;
        d=y0-mu; v=fmaf(d,d,v); d=y1-mu; v=fmaf(d,d,v);
        d=y2-mu; v=fmaf(d,d,v); d=y3-mu; v=fmaf(d,d,v);
        d=y4-mu; v=fmaf(d,d,v); d=y5-mu; v=fmaf(d,d,v);
        d=y6-mu; v=fmaf(d,d,v); d=y7-mu; v=fmaf(d,d,v);
        v += __shfl_xor(v, 16);
        v += __shfl_xor(v, 32);
        float rs = rsqrtf(v*(1.f/32.f) + 1e-5f);
        float4 ga = *(const float4*)(lg + q*8);
        float4 gb = *(const float4*)(lg + q*8 + 4);
        float4 oa = *(const float4*)(lb + q*8);
        float4 ob = *(const float4*)(lb + q*8 + 4);
        y0 = fmaf((y0-mu)*rs, ga.x, oa.x); y1 = fmaf((y1-mu)*rs, ga.y, oa.y);
        y2 = fmaf((y2-mu)*rs, ga.z, oa.z); y3 = fmaf((y3-mu)*rs, ga.w, oa.w);
        y4 = fmaf((y4-mu)*rs, gb.x, ob.x); y5 = fmaf((y5-mu)*rs, gb.y, ob.y);
        y6 = fmaf((y6-mu)*rs, gb.z, ob.z); y7 = fmaf((y7-mu)*rs, gb.w, ob.w);
    }
    uint4 w;
    w.x = pk2(y0, y1); w.y = pk2(y2, y3); w.z = pk2(y4, y5); w.w = pk2(y6, y7);
    *(uint4*)(Y + n*36 + q*4) = w;
}

// ---------------------------------------------------------------------------
// Wave-level deep MLP. Input features already packed into LDS Y rows
// (dwords: feature pairs (2t,2t+1)). KP = padded input K (32 or 64).
// Packed weights Wp: [Bin 32*(KP/2)] [Bh 32*32*16] [Bo 16*16] (dwords).
// Returns output-layer MFMA D (pre-bias), n-half 0 only (dout<=16).
// ---------------------------------------------------------------------------
template<int KP, bool LN>
__device__ __forceinline__ f32x4 mlp_core(
    const u32* __restrict__ Wp,
    const float* __restrict__ bin, const float* __restrict__ bh,
    const float* __restrict__ lng, const float* __restrict__ lnb,
    float* X, u32* Y, int n, int q)
{
    constexpr int INDW = 32*(KP/2);
    const u32* Bin = Wp;
    const u32* Bh  = Wp + INDW;
    const u32* Bo  = Wp + INDW + 16384;
    U4 c;
    f32x4 D0 = {0.f,0.f,0.f,0.f}, D1 = {0.f,0.f,0.f,0.f};
    #pragma unroll
    for (int T = 0; T < KP/32; ++T) {
        c.u = *(const uint4*)(Y + n*36 + T*16 + q*4);              bf16x8 a  = c.h;
        c.u = *(const uint4*)(Bin + (n     )*(KP/2) + T*16 + q*4); bf16x8 b0 = c.h;
        c.u = *(const uint4*)(Bin + (n + 16)*(KP/2) + T*16 + q*4); bf16x8 b1 = c.h;
        D0 = __builtin_amdgcn_mfma_f32_16x16x32_bf16(a, b0, D0, 0, 0, 0);
        D1 = __builtin_amdgcn_mfma_f32_16x16x32_bf16(a, b1, D1, 0, 0, 0);
    }
    epilogue<LN>(D0, D1, bin, lng, lnb, X, Y, n, q);
    #pragma unroll 1
    for (int l = 0; l < 32; ++l) {
        c.u = *(const uint4*)(Y + n*36 + q*4);       bf16x8 a  = c.h;
        const u32* Bl = Bh + l*512;
        c.u = *(const uint4*)(Bl + n*16 + q*4);      bf16x8 b0 = c.h;
        c.u = *(const uint4*)(Bl + (n+16)*16 + q*4); bf16x8 b1 = c.h;
        f32x4 Z = {0.f,0.f,0.f,0.f};
        f32x4 E0 = __builtin_amdgcn_mfma_f32_16x16x32_bf16(a, b0, Z, 0, 0, 0);
        f32x4 E1 = __builtin_amdgcn_mfma_f32_16x16x32_bf16(a, b1, Z, 0, 0, 0);
        epilogue<LN>(E0, E1, bh + l*32,
                     LN ? (lng + (l+1)*32) : lng,
                     LN ? (lnb + (l+1)*32) : lnb, X, Y, n, q);
    }
    c.u = *(const uint4*)(Y + n*36 + q*4);  bf16x8 a  = c.h;
    c.u = *(const uint4*)(Bo + n*16 + q*4); bf16x8 bo = c.h;
    f32x4 Z = {0.f,0.f,0.f,0.f};
    return __builtin_amdgcn_mfma_f32_16x16x32_bf16(a, bo, Z, 0, 0, 0);
}

// ---------------------------------------------------------------------------
// Weight packing: B[n][dword t] = bf16pair(W[2t][n], W[2t+1][n]), zero-padded.
// ---------------------------------------------------------------------------
__global__ __launch_bounds__(256) void pack_kernel(
    const float* __restrict__ Win, const float* __restrict__ Wh,
    const float* __restrict__ Wout, u32* __restrict__ dst,
    int din, int dout, int KP)
{
    int t = blockIdx.x * blockDim.x + threadIdx.x;
    int indw = 32*(KP/2);
    int tot = indw + 16384 + 256;
    if (t >= tot) return;
    float lo, hi;
    if (t < indw) {
        int nrow = t / (KP/2), dw = t % (KP/2);
        int k0 = 2*dw, k1 = k0 + 1;
        lo = (k0 < din) ? Win[k0*32 + nrow] : 0.f;
        hi = (k1 < din) ? Win[k1*32 + nrow] : 0.f;
    } else if (t < indw + 16384) {
        int u = t - indw; int l = u >> 9; int v = u & 511;
        int nrow = v >> 4; int dw = v & 15;
        lo = Wh[l*1024 + (2*dw)*32 + nrow];
        hi = Wh[l*1024 + (2*dw+1)*32 + nrow];
    } else {
        int u = t - indw - 16384; int nrow = u >> 4; int dw = u & 15;
        lo = (nrow < dout) ? Wout[(2*dw)*dout + nrow] : 0.f;
        hi = (nrow < dout) ? Wout[(2*dw+1)*dout + nrow] : 0.f;
    }
    dst[t] = pk2(lo, hi);
}

// ---------------------------------------------------------------------------
// Kernels. Block = 256 thr = 4 waves; each wave owns 16 elements.
// ---------------------------------------------------------------------------
#define WAVE_SETUP \
    __shared__ float Xs[4*576]; \
    __shared__ u32   Ys[4*576]; \
    const int lane = threadIdx.x & 63; \
    const int wid  = threadIdx.x >> 6; \
    const int n = lane & 15, q = lane >> 4; \
    float* X = Xs + wid*576; \
    u32*   Y = Ys + wid*576;

__global__ __launch_bounds__(256, 4) void encode_kernel(
    const float* __restrict__ nodes, const float* __restrict__ edges,
    const float* __restrict__ gvec,
    const int* __restrict__ senders, const int* __restrict__ receivers,
    const u32* __restrict__ Wne, const float* __restrict__ ne_bin,
    const float* __restrict__ ne_bh, const float* __restrict__ ne_bout,
    const u32* __restrict__ Wed, const float* __restrict__ ed_bin,
    const float* __restrict__ ed_bh, const float* __restrict__ ed_bout,
    float* __restrict__ ve, float* __restrict__ ee)
{
    WAVE_SETUP
    const bool edge_stage = blockIdx.x >= 1024;
    const int lb = edge_stage ? (blockIdx.x - 1024) : blockIdx.x;
    const int e0 = (lb*4 + wid) * 16;
    const int e  = e0 + n;
    const int b  = e >> 15;
    float f[8];
    #pragma unroll
    for (int i = 0; i < 8; ++i) f[i] = 0.f;
    if (!edge_stage) {
        if (q == 0) {
            #pragma unroll
            for (int i = 0; i < 6; ++i) f[i] = nodes[(size_t)e*6 + i];
            f[6] = gvec[b];
        }
    } else {
        if (q == 0) {
            int s = senders[e], r = receivers[e];
            const float* ps = nodes + ((size_t)b*NN + s)*6;
            const float* pr = nodes + ((size_t)b*NN + r)*6;
            float r0 = ps[0]-pr[0], r1 = ps[1]-pr[1], r2 = ps[2]-pr[2];
            f[0] = edges[e]; f[1] = r0; f[2] = r1; f[3] = r2;
            f[4] = sqrtf(r0*r0 + r1*r1 + r2*r2);
        }
    }
    uint4 w; w.x=pk2(f[0],f[1]); w.y=pk2(f[2],f[3]); w.z=pk2(f[4],f[5]); w.w=pk2(f[6],f[7]);
    *(uint4*)(Y + n*36 + q*4) = w;

    const u32*   Wp   = edge_stage ? Wed    : Wne;
    const float* pbin = edge_stage ? ed_bin : ne_bin;
    const float* pbh  = edge_stage ? ed_bh  : ne_bh;
    const float* pbo  = edge_stage ? ed_bout: ne_bout;
    float* dst        = edge_stage ? ee     : ve;
    f32x4 D = mlp_core<32, false>(Wp, pbin, pbh, pbin, pbin, X, Y, n, q);
    float bo = pbo[n];
    #pragma unroll
    for (int r = 0; r < 4; ++r)
        dst[(size_t)(e0 + q*4 + r)*16 + n] = fmaxf(D[r] + bo, 0.f);
}

__global__ __launch_bounds__(256, 4) void edge_update_kernel(
    const float* __restrict__ gvec,
    const int* __restrict__ senders, const int* __restrict__ receivers,
    const float* __restrict__ ve, float* __restrict__ ee, float* __restrict__ agg,
    const u32* __restrict__ Wp, const float* __restrict__ bin,
    const float* __restrict__ bh, const float* __restrict__ bout,
    const float* __restrict__ lng, const float* __restrict__ lnb)
{
    WAVE_SETUP
    const int e0 = (blockIdx.x*4 + wid) * 16;
    const int e  = e0 + n;
    const int b  = e >> 15;
    int s = senders[e], r = receivers[e];
    const float* eep = ee + (size_t)e*16;
    const float* vsp = ve + ((size_t)b*NN + s)*16;
    const float* vrp = ve + ((size_t)b*NN + r)*16;
    // octet q: [ee0 ee1 vs0 vs1]
    {
        const float* src = (q == 0) ? eep : (q == 1) ? (eep+8) : (q == 2) ? vsp : (vsp+8);
        float4 a = *(const float4*)src;
        float4 c = *(const float4*)(src + 4);
        uint4 w; w.x=pk2(a.x,a.y); w.y=pk2(a.z,a.w); w.z=pk2(c.x,c.y); w.w=pk2(c.z,c.w);
        *(uint4*)(Y + n*36 + q*4) = w;
    }
    // octet q+4: [vr0 vr1 g zeros]
    {
        uint4 w;
        if (q < 2) {
            const float* src = (q == 0) ? vrp : (vrp+8);
            float4 a = *(const float4*)src;
            float4 c = *(const float4*)(src + 4);
            w.x=pk2(a.x,a.y); w.y=pk2(a.z,a.w); w.z=pk2(c.x,c.y); w.w=pk2(c.z,c.w);
        } else if (q == 2) {
            w.x = pk2(gvec[b], 0.f); w.y = 0u; w.z = 0u; w.w = 0u;
        } else {
            w.x = 0u; w.y = 0u; w.z = 0u; w.w = 0u;
        }
        *(uint4*)(Y + n*36 + (q+4)*4) = w;
    }
    f32x4 D = mlp_core<64, true>(Wp, bin, bh, lng, lnb, X, Y, n, q);
    float bo = bout[n];
    #pragma unroll
    for (int rr = 0; rr < 4; ++rr) {
        int em = e0 + q*4 + rr;
        float v = fmaxf(D[rr] + bo, 0.f);
        ee[(size_t)em*16 + n] = v;
        int rc = receivers[em];
        atomicAdd(agg + ((size_t)(em >> 15)*NN + rc)*16 + n, v);
    }
}

__global__ __launch_bounds__(256, 4) void node_update_kernel(
    const float* __restrict__ gvec,
    const float* __restrict__ agg, float* __restrict__ ve,
    const u32* __restrict__ Wp, const float* __restrict__ bin,
    const float* __restrict__ bh, const float* __restrict__ bout,
    const float* __restrict__ lng, const float* __restrict__ lnb)
{
    WAVE_SETUP
    const int e0 = (blockIdx.x*4 + wid) * 16;
    const int e  = e0 + n;
    const int b  = e >> 15;
    const float* agp = agg + (size_t)e*16;
    const float* vep = ve  + (size_t)e*16;
    // octet q: [agg0 agg1 ve0 ve1]
    {
        const float* src = (q == 0) ? agp : (q == 1) ? (agp+8) : (q == 2) ? vep : (vep+8);
        float4 a = *(const float4*)src;
        float4 c = *(const float4*)(src + 4);
        uint4 w; w.x=pk2(a.x,a.y); w.y=pk2(a.z,a.w); w.z=pk2(c.x,c.y); w.w=pk2(c.z,c.w);
        *(uint4*)(Y + n*36 + q*4) = w;
    }
    // octet q+4: [g zeros zeros zeros]
    {
        uint4 w;
        if (q == 0) { w.x = pk2(gvec[b], 0.f); w.y = 0u; w.z = 0u; w.w = 0u; }
        else        { w.x = 0u; w.y = 0u; w.z = 0u; w.w = 0u; }
        *(uint4*)(Y + n*36 + (q+4)*4) = w;
    }
    f32x4 D = mlp_core<64, true>(Wp, bin, bh, lng, lnb, X, Y, n, q);
    float bo = bout[n];
    #pragma unroll
    for (int rr = 0; rr < 4; ++rr) {
        int em = e0 + q*4 + rr;
        ve[(size_t)em*16 + n] = fmaxf(D[rr] + bo, 0.f);
    }
}

__global__ __launch_bounds__(256, 4) void decode_kernel(
    const float* __restrict__ ve,
    const u32* __restrict__ Wp, const float* __restrict__ bin,
    const float* __restrict__ bh, const float* __restrict__ bout,
    float* __restrict__ out)
{
    WAVE_SETUP
    const int e0 = (blockIdx.x*4 + wid) * 16;
    const int e  = e0 + n;
    const float* vep = ve + (size_t)e*16;
    {
        uint4 w;
        if (q < 2) {
            const float* src = (q == 0) ? vep : (vep+8);
            float4 a = *(const float4*)src;
            float4 c = *(const float4*)(src + 4);
            w.x=pk2(a.x,a.y); w.y=pk2(a.z,a.w); w.z=pk2(c.x,c.y); w.w=pk2(c.z,c.w);
        } else {
            w.x = 0u; w.y = 0u; w.z = 0u; w.w = 0u;
        }
        *(uint4*)(Y + n*36 + q*4) = w;
    }
    f32x4 D = mlp_core<32, false>(Wp, bin, bh, bin, bin, X, Y, n, q);
    if (n < 3) {
        float bo = bout[n];
        #pragma unroll
        for (int rr = 0; rr < 4; ++rr) {
            int em = e0 + q*4 + rr;
            out[(size_t)em*3 + n] = fmaxf(D[rr] + bo, 0.f);
        }
    }
}

// ---------------------------------------------------------------------------
// launch
// ---------------------------------------------------------------------------
extern "C" void kernel_launch(void* const* d_in, const int* in_sizes, int n_in,
                              void* d_out, int out_size, void* d_ws, size_t ws_size,
                              hipStream_t stream)
{
    const float* nodes     = (const float*)d_in[0];
    const float* edges     = (const float*)d_in[1];
    const float* gvec      = (const float*)d_in[2];
    const int*   senders   = (const int*)  d_in[3];
    const int*   receivers = (const int*)  d_in[4];

    const float* ne_Win  = (const float*)d_in[5];
    const float* ne_bin  = (const float*)d_in[6];
    const float* ne_Wh   = (const float*)d_in[7];
    const float* ne_bh   = (const float*)d_in[8];
    const float* ne_Wout = (const float*)d_in[9];
    const float* ne_bout = (const float*)d_in[10];

    const float* ed_Win  = (const float*)d_in[11];
    const float* ed_bin  = (const float*)d_in[12];
    const float* ed_Wh   = (const float*)d_in[13];
    const float* ed_bh   = (const float*)d_in[14];
    const float* ed_Wout = (const float*)d_in[15];
    const float* ed_bout = (const float*)d_in[16];

    const float* pe_Win  = (const float*)d_in[17];
    const float* pe_bin  = (const float*)d_in[18];
    const float* pe_Wh   = (const float*)d_in[19];
    const float* pe_bh   = (const float*)d_in[20];
    const float* pe_Wout = (const float*)d_in[21];
    const float* pe_bout = (const float*)d_in[22];
    const float* pe_lng  = (const float*)d_in[23];
    const float* pe_lnb  = (const float*)d_in[24];

    const float* pv_Win  = (const float*)d_in[25];
    const float* pv_bin  = (const float*)d_in[26];
    const float* pv_Wh   = (const float*)d_in[27];
    const float* pv_bh   = (const float*)d_in[28];
    const float* pv_Wout = (const float*)d_in[29];
    const float* pv_bout = (const float*)d_in[30];
    const float* pv_lng  = (const float*)d_in[31];
    const float* pv_lnb  = (const float*)d_in[32];

    const float* de_Win  = (const float*)d_in[33];
    const float* de_bin  = (const float*)d_in[34];
    const float* de_Wh   = (const float*)d_in[35];
    const float* de_bh   = (const float*)d_in[36];
    const float* de_Wout = (const float*)d_in[37];
    const float* de_bout = (const float*)d_in[38];

    // workspace: ve | ee | agg (4 MB each) | packed bf16 weights (~347 KB)
    float* ve  = (float*)d_ws;
    float* ee  = ve + (size_t)1048576;
    float* agg = ee + (size_t)1048576;
    u32* Wne = (u32*)(agg + (size_t)1048576);
    u32* Wed = Wne + 17152;
    u32* Wpe = Wed + 17152;
    u32* Wpv = Wpe + 17664;
    u32* Wde = Wpv + 17664;

    const dim3 blk(256);

    pack_kernel<<<70, blk, 0, stream>>>(ne_Win, ne_Wh, ne_Wout, Wne,  7, 16, 32);
    pack_kernel<<<70, blk, 0, stream>>>(ed_Win, ed_Wh, ed_Wout, Wed,  5, 16, 32);
    pack_kernel<<<70, blk, 0, stream>>>(pe_Win, pe_Wh, pe_Wout, Wpe, 49, 16, 64);
    pack_kernel<<<70, blk, 0, stream>>>(pv_Win, pv_Wh, pv_Wout, Wpv, 33, 16, 64);
    pack_kernel<<<70, blk, 0, stream>>>(de_Win, de_Wh, de_Wout, Wde, 16,  3, 32);

    encode_kernel<<<2048, blk, 0, stream>>>(nodes, edges, gvec, senders, receivers,
        Wne, ne_bin, ne_bh, ne_bout,
        Wed, ed_bin, ed_bh, ed_bout, ve, ee);

    for (int step = 0; step < 2; ++step) {
        hipMemsetAsync(agg, 0, (size_t)BB * NN * 16 * sizeof(float), stream);
        edge_update_kernel<<<1024, blk, 0, stream>>>(gvec, senders, receivers,
            ve, ee, agg, Wpe, pe_bin, pe_bh, pe_bout, pe_lng, pe_lnb);
        node_update_kernel<<<1024, blk, 0, stream>>>(gvec, agg, ve,
            Wpv, pv_bin, pv_bh, pv_bout, pv_lng, pv_lnb);
    }

    decode_kernel<<<1024, blk, 0, stream>>>(ve,
        Wde, de_bin, de_bh, de_bout, (float*)d_out);
}

// Round 5
// 368.521 us; speedup vs baseline: 4.7826x; 1.0781x over previous
//
#include <hip/hip_runtime.h>

#define BB 2
#define NN 32768
#define EN 32768

typedef unsigned int u32;
typedef __attribute__((ext_vector_type(8))) short bf16x8;
typedef __attribute__((ext_vector_type(4))) float f32x4;

union U4 { uint4 u; bf16x8 h; };

// ---------------------------------------------------------------------------
// f32 pair -> packed bf16 dword (RNE). HW instr on gfx950 when available.
// ---------------------------------------------------------------------------
#if defined(__has_builtin)
#if __has_builtin(__builtin_amdgcn_cvt_pk_bf16_f32)
#define HAVE_CVT_PK 1
#endif
#endif

#ifdef HAVE_CVT_PK
typedef __attribute__((ext_vector_type(2))) __bf16 bfv2;
__device__ __forceinline__ u32 pk2(float lo, float hi) {
    bfv2 v = __builtin_amdgcn_cvt_pk_bf16_f32(lo, hi);
    return __builtin_bit_cast(u32, v);
}
#else
__device__ __forceinline__ u32 pk2(float lo, float hi) {
    u32 a = __builtin_bit_cast(u32, lo);
    u32 b = __builtin_bit_cast(u32, hi);
    a += 0x7FFFu + ((a >> 16) & 1u);
    b += 0x7FFFu + ((b >> 16) & 1u);
    return (a >> 16) | (b & 0xFFFF0000u);
}
#endif

__device__ __forceinline__ float ulo(u32 d) { return __builtin_bit_cast(float, d << 16); }
__device__ __forceinline__ float uhi(u32 d) { return __builtin_bit_cast(float, d & 0xFFFF0000u); }

// ---------------------------------------------------------------------------
// Per-layer epilogue with pi-permuted k-layout.
// D0/D1: C-layout (lane (n,q): D0[r]=feat n, D1[r]=feat n+16 of elem m=q*4+r).
// One pk2 per r gives the transpose payload dword (feat pair (n, n+16)).
// LDS Y[feature_row][element], row stride 20 dwords (16B-aligned rows,
// uniform banks on b128 write; 2-way (free) on the 4 b32 reads).
// Read-back at (q*4+i)*20+n = this lane's a-frag dwords for the next MFMA:
// dword i of lane (m=n, q) <-> features (q*4+i, q*4+i+16)  [the pi layout].
// Wave-private -> no barriers.
// ---------------------------------------------------------------------------
template<bool LN>
__device__ __forceinline__ bf16x8 transform(
    f32x4 D0, f32x4 D1, float blo, float bhi,
    const float* __restrict__ lg, const float* __restrict__ lb,
    u32* Y, int n, int q)
{
    uint4 w;
    w.x = pk2(fmaxf(D0[0] + blo, 0.f), fmaxf(D1[0] + bhi, 0.f));
    w.y = pk2(fmaxf(D0[1] + blo, 0.f), fmaxf(D1[1] + bhi, 0.f));
    w.z = pk2(fmaxf(D0[2] + blo, 0.f), fmaxf(D1[2] + bhi, 0.f));
    w.w = pk2(fmaxf(D0[3] + blo, 0.f), fmaxf(D1[3] + bhi, 0.f));
    *(uint4*)(Y + n*20 + q*4) = w;
    u32 d0 = Y[(q*4+0)*20 + n];
    u32 d1 = Y[(q*4+1)*20 + n];
    u32 d2 = Y[(q*4+2)*20 + n];
    u32 d3 = Y[(q*4+3)*20 + n];
    if (LN) {
        float x0 = ulo(d0), x1 = ulo(d1), x2 = ulo(d2), x3 = ulo(d3);
        float z0 = uhi(d0), z1 = uhi(d1), z2 = uhi(d2), z3 = uhi(d3);
        float s = ((x0+x1)+(x2+x3)) + ((z0+z1)+(z2+z3));
        float s2 = 0.f;
        s2 = fmaf(x0,x0,s2); s2 = fmaf(x1,x1,s2); s2 = fmaf(x2,x2,s2); s2 = fmaf(x3,x3,s2);
        s2 = fmaf(z0,z0,s2); s2 = fmaf(z1,z1,s2); s2 = fmaf(z2,z2,s2); s2 = fmaf(z3,z3,s2);
        s  += __shfl_xor(s, 16);  s  += __shfl_xor(s, 32);
        s2 += __shfl_xor(s2, 16); s2 += __shfl_xor(s2, 32);
        float mu  = s * (1.f/32.f);
        float var = fmaf(-mu, mu, s2 * (1.f/32.f));
        float rs  = rsqrtf(var + 1e-5f);
        float4 gl  = *(const float4*)(lg + q*4);
        float4 gh  = *(const float4*)(lg + q*4 + 16);
        float4 ol  = *(const float4*)(lb + q*4);
        float4 oh  = *(const float4*)(lb + q*4 + 16);
        float sl0 = rs*gl.x, sl1 = rs*gl.y, sl2 = rs*gl.z, sl3 = rs*gl.w;
        float sh0 = rs*gh.x, sh1 = rs*gh.y, sh2 = rs*gh.z, sh3 = rs*gh.w;
        x0 = fmaf(x0, sl0, fmaf(-mu, sl0, ol.x));
        x1 = fmaf(x1, sl1, fmaf(-mu, sl1, ol.y));
        x2 = fmaf(x2, sl2, fmaf(-mu, sl2, ol.z));
        x3 = fmaf(x3, sl3, fmaf(-mu, sl3, ol.w));
        z0 = fmaf(z0, sh0, fmaf(-mu, sh0, oh.x));
        z1 = fmaf(z1, sh1, fmaf(-mu, sh1, oh.y));
        z2 = fmaf(z2, sh2, fmaf(-mu, sh2, oh.z));
        z3 = fmaf(z3, sh3, fmaf(-mu, sh3, oh.w));
        d0 = pk2(x0, z0); d1 = pk2(x1, z1); d2 = pk2(x2, z2); d3 = pk2(x3, z3);
    }
    U4 c; c.u.x = d0; c.u.y = d1; c.u.z = d2; c.u.w = d3;
    return c.h;
}

// ---------------------------------------------------------------------------
// Wave-level deep MLP with register-double-buffered weight prefetch.
// Packed weights Wp (pi layout): [Bin 32*(KT*16)] [Bh 32*512] [Bo 256] dwords.
// ---------------------------------------------------------------------------
template<int KT, bool LN>
__device__ __forceinline__ f32x4 mlp_core(
    const bf16x8* a_in, const u32* __restrict__ Wp,
    const float* __restrict__ bin, const float* __restrict__ bh,
    const float* __restrict__ lng, const float* __restrict__ lnb,
    u32* Y, int n, int q)
{
    const u32* Bh = Wp + 32*KT*16;
    const u32* Bo = Bh + 16384;
    U4 c;
    f32x4 D0 = {0.f,0.f,0.f,0.f}, D1 = {0.f,0.f,0.f,0.f};
    #pragma unroll
    for (int T = 0; T < KT; ++T) {
        c.u = *(const uint4*)(Wp + (size_t)n*(KT*16) + T*16 + q*4);      bf16x8 b0 = c.h;
        c.u = *(const uint4*)(Wp + (size_t)(n+16)*(KT*16) + T*16 + q*4); bf16x8 b1 = c.h;
        D0 = __builtin_amdgcn_mfma_f32_16x16x32_bf16(a_in[T], b0, D0, 0, 0, 0);
        D1 = __builtin_amdgcn_mfma_f32_16x16x32_bf16(a_in[T], b1, D1, 0, 0, 0);
    }
    // prefetch layer-0 weights before the input epilogue
    c.u = *(const uint4*)(Bh + n*16 + q*4);       bf16x8 w0 = c.h;
    c.u = *(const uint4*)(Bh + (n+16)*16 + q*4);  bf16x8 w1 = c.h;
    bf16x8 aa = transform<LN>(D0, D1, bin[n], bin[n+16], lng, lnb, Y, n, q);
    #pragma unroll 1
    for (int l = 0; l < 32; ++l) {
        const int lnx = (l+1 < 32) ? l+1 : 31;
        const u32* Bn = Bh + lnx*512;
        c.u = *(const uint4*)(Bn + n*16 + q*4);       bf16x8 nw0 = c.h;
        c.u = *(const uint4*)(Bn + (n+16)*16 + q*4);  bf16x8 nw1 = c.h;
        float blo = bh[l*32 + n], bhi = bh[l*32 + n + 16];
        f32x4 Z = {0.f,0.f,0.f,0.f};
        f32x4 E0 = __builtin_amdgcn_mfma_f32_16x16x32_bf16(aa, w0, Z, 0, 0, 0);
        f32x4 E1 = __builtin_amdgcn_mfma_f32_16x16x32_bf16(aa, w1, Z, 0, 0, 0);
        aa = transform<LN>(E0, E1, blo, bhi,
                           lng + (l+1)*32, lnb + (l+1)*32, Y, n, q);
        w0 = nw0; w1 = nw1;
    }
    c.u = *(const uint4*)(Bo + n*16 + q*4); bf16x8 bo = c.h;
    f32x4 Z = {0.f,0.f,0.f,0.f};
    return __builtin_amdgcn_mfma_f32_16x16x32_bf16(aa, bo, Z, 0, 0, 0);
}

// ---------------------------------------------------------------------------
// Weight packing (pi layout): dword d of row n = (W[base+d][n], W[base+d+16][n])
// ---------------------------------------------------------------------------
__global__ __launch_bounds__(256) void pack_kernel(
    const float* __restrict__ Win, const float* __restrict__ Wh,
    const float* __restrict__ Wout, u32* __restrict__ dst,
    int din, int dout, int KP)
{
    int t = blockIdx.x * blockDim.x + threadIdx.x;
    int indw = 32*(KP/2);
    int tot = indw + 16384 + 256;
    if (t >= tot) return;
    float lo, hi;
    if (t < indw) {
        int nrow = t / (KP/2), rem = t % (KP/2);
        int T = rem >> 4, d = rem & 15;
        int klo = T*32 + d, khi = klo + 16;
        lo = (klo < din) ? Win[klo*32 + nrow] : 0.f;
        hi = (khi < din) ? Win[khi*32 + nrow] : 0.f;
    } else if (t < indw + 16384) {
        int u = t - indw; int l = u >> 9; int v = u & 511;
        int nrow = v >> 4; int d = v & 15;
        lo = Wh[l*1024 + d*32 + nrow];
        hi = Wh[l*1024 + (d+16)*32 + nrow];
    } else {
        int u = t - indw - 16384; int nrow = u >> 4; int d = u & 15;
        lo = (nrow < dout) ? Wout[d*dout + nrow] : 0.f;
        hi = (nrow < dout) ? Wout[(d+16)*dout + nrow] : 0.f;
    }
    dst[t] = pk2(lo, hi);
}

// ---------------------------------------------------------------------------
// Kernels. Block = 256 thr = 4 waves; each wave owns 16 elements.
// LDS: 320 dwords per wave (16 rows x 20), 5 KB/block -> 4 blocks/CU fine.
// ---------------------------------------------------------------------------
#define WAVE_SETUP \
    __shared__ __align__(16) u32 Ys[4*320]; \
    const int lane = threadIdx.x & 63; \
    const int wid  = threadIdx.x >> 6; \
    const int n = lane & 15, q = lane >> 4; \
    u32* Y = Ys + wid*320;

__global__ __launch_bounds__(256, 4) void encode_kernel(
    const float* __restrict__ nodes, const float* __restrict__ edges,
    const float* __restrict__ gvec,
    const int* __restrict__ senders, const int* __restrict__ receivers,
    const u32* __restrict__ Wne, const float* __restrict__ ne_bin,
    const float* __restrict__ ne_bh, const float* __restrict__ ne_bout,
    const u32* __restrict__ Wed, const float* __restrict__ ed_bin,
    const float* __restrict__ ed_bh, const float* __restrict__ ed_bout,
    float* __restrict__ ve, float* __restrict__ ee)
{
    WAVE_SETUP
    const bool edge_stage = blockIdx.x >= 1024;
    const int lb = edge_stage ? (blockIdx.x - 1024) : blockIdx.x;
    const int e0 = (lb*4 + wid) * 16;
    const int e  = e0 + n;        // this lane stages element m = n
    const int b  = e >> 15;
    bf16x8 a0;
    {
        uint4 w; w.x = 0u; w.y = 0u; w.z = 0u; w.w = 0u;
        if (!edge_stage) {
            if (q == 0) {
                float2 v01 = *(const float2*)(nodes + (size_t)e*6);
                float2 v23 = *(const float2*)(nodes + (size_t)e*6 + 2);
                w.x = pk2(v01.x, 0.f); w.y = pk2(v01.y, 0.f);
                w.z = pk2(v23.x, 0.f); w.w = pk2(v23.y, 0.f);
            } else if (q == 1) {
                float2 v45 = *(const float2*)(nodes + (size_t)e*6 + 4);
                w.x = pk2(v45.x, 0.f); w.y = pk2(v45.y, 0.f);
                w.z = pk2(gvec[b], 0.f);
            }
        } else {
            if (q < 2) {
                int s = senders[e], r = receivers[e];
                const float* ps = nodes + ((size_t)b*NN + s)*6;
                const float* pr = nodes + ((size_t)b*NN + r)*6;
                float2 s01 = *(const float2*)ps; float s2v = ps[2];
                float2 r01 = *(const float2*)pr; float r2v = pr[2];
                float r0 = s01.x - r01.x, r1 = s01.y - r01.y, r2 = s2v - r2v;
                if (q == 0) {
                    w.x = pk2(edges[e], 0.f); w.y = pk2(r0, 0.f);
                    w.z = pk2(r1, 0.f);       w.w = pk2(r2, 0.f);
                } else {
                    w.x = pk2(sqrtf(r0*r0 + r1*r1 + r2*r2), 0.f);
                }
            }
        }
        U4 c; c.u = w; a0 = c.h;
    }
    const u32*   Wp   = edge_stage ? Wed    : Wne;
    const float* pbin = edge_stage ? ed_bin : ne_bin;
    const float* pbh  = edge_stage ? ed_bh  : ne_bh;
    const float* pbo  = edge_stage ? ed_bout: ne_bout;
    float* dst        = edge_stage ? ee     : ve;
    f32x4 D = mlp_core<1, false>(&a0, Wp, pbin, pbh, pbin, pbin, Y, n, q);
    float bo = pbo[n];
    #pragma unroll
    for (int r = 0; r < 4; ++r)
        dst[(size_t)(e0 + q*4 + r)*16 + n] = fmaxf(D[r] + bo, 0.f);
}

__global__ __launch_bounds__(256, 4) void edge_update_kernel(
    const float* __restrict__ gvec,
    const int* __restrict__ senders, const int* __restrict__ receivers,
    const float* __restrict__ ve, float* __restrict__ ee, float* __restrict__ agg,
    const u32* __restrict__ Wp, const float* __restrict__ bin,
    const float* __restrict__ bh, const float* __restrict__ bout,
    const float* __restrict__ lng, const float* __restrict__ lnb)
{
    WAVE_SETUP
    const int e0 = (blockIdx.x*4 + wid) * 16;
    const int e  = e0 + n;
    const int b  = e >> 15;
    const int s  = senders[e], r_ = receivers[e];
    // x = [ee(0..15) vs(16..31) vr(32..47) g(48) 0...]
    float4 eev = *(const float4*)(ee + (size_t)e*16 + q*4);
    float4 vsv = *(const float4*)(ve + ((size_t)b*NN + s)*16 + q*4);
    float4 vrv = *(const float4*)(ve + ((size_t)b*NN + r_)*16 + q*4);
    float g = gvec[b];
    bf16x8 a[2];
    {
        U4 c;
        c.u.x = pk2(eev.x, vsv.x); c.u.y = pk2(eev.y, vsv.y);
        c.u.z = pk2(eev.z, vsv.z); c.u.w = pk2(eev.w, vsv.w);
        a[0] = c.h;
        c.u.x = pk2(vrv.x, (q == 0) ? g : 0.f);
        c.u.y = pk2(vrv.y, 0.f);
        c.u.z = pk2(vrv.z, 0.f);
        c.u.w = pk2(vrv.w, 0.f);
        a[1] = c.h;
    }
    f32x4 D = mlp_core<2, true>(a, Wp, bin, bh, lng, lnb, Y, n, q);
    float bo = bout[n];
    #pragma unroll
    for (int rr = 0; rr < 4; ++rr) {
        int em = e0 + q*4 + rr;
        float v = fmaxf(D[rr] + bo, 0.f);
        ee[(size_t)em*16 + n] = v;
        int rc = receivers[em];
        atomicAdd(agg + ((size_t)(em >> 15)*NN + rc)*16 + n, v);
    }
}

__global__ __launch_bounds__(256, 4) void node_update_kernel(
    const float* __restrict__ gvec,
    const float* __restrict__ agg, float* __restrict__ ve,
    const u32* __restrict__ Wp, const float* __restrict__ bin,
    const float* __restrict__ bh, const float* __restrict__ bout,
    const float* __restrict__ lng, const float* __restrict__ lnb)
{
    WAVE_SETUP
    const int e0 = (blockIdx.x*4 + wid) * 16;
    const int e  = e0 + n;
    const int b  = e >> 15;
    // x = [agg(0..15) ve(16..31) g(32) 0...]
    float4 agv = *(const float4*)(agg + (size_t)e*16 + q*4);
    float4 vev = *(const float4*)(ve  + (size_t)e*16 + q*4);
    float g = gvec[b];
    bf16x8 a[2];
    {
        U4 c;
        c.u.x = pk2(agv.x, vev.x); c.u.y = pk2(agv.y, vev.y);
        c.u.z = pk2(agv.z, vev.z); c.u.w = pk2(agv.w, vev.w);
        a[0] = c.h;
        c.u.x = (q == 0) ? pk2(g, 0.f) : 0u;
        c.u.y = 0u; c.u.z = 0u; c.u.w = 0u;
        a[1] = c.h;
    }
    f32x4 D = mlp_core<2, true>(a, Wp, bin, bh, lng, lnb, Y, n, q);
    float bo = bout[n];
    #pragma unroll
    for (int rr = 0; rr < 4; ++rr) {
        int em = e0 + q*4 + rr;
        ve[(size_t)em*16 + n] = fmaxf(D[rr] + bo, 0.f);
    }
}

__global__ __launch_bounds__(256, 4) void decode_kernel(
    const float* __restrict__ ve,
    const u32* __restrict__ Wp, const float* __restrict__ bin,
    const float* __restrict__ bh, const float* __restrict__ bout,
    float* __restrict__ out)
{
    WAVE_SETUP
    const int e0 = (blockIdx.x*4 + wid) * 16;
    const int e  = e0 + n;
    float4 vev = *(const float4*)(ve + (size_t)e*16 + q*4);
    bf16x8 a0;
    {
        U4 c;
        c.u.x = pk2(vev.x, 0.f); c.u.y = pk2(vev.y, 0.f);
        c.u.z = pk2(vev.z, 0.f); c.u.w = pk2(vev.w, 0.f);
        a0 = c.h;
    }
    f32x4 D = mlp_core<1, false>(&a0, Wp, bin, bh, bin, bin, Y, n, q);
    if (n < 3) {
        float bo = bout[n];
        #pragma unroll
        for (int rr = 0; rr < 4; ++rr) {
            int em = e0 + q*4 + rr;
            out[(size_t)em*3 + n] = fmaxf(D[rr] + bo, 0.f);
        }
    }
}

// ---------------------------------------------------------------------------
// launch
// ---------------------------------------------------------------------------
extern "C" void kernel_launch(void* const* d_in, const int* in_sizes, int n_in,
                              void* d_out, int out_size, void* d_ws, size_t ws_size,
                              hipStream_t stream)
{
    const float* nodes     = (const float*)d_in[0];
    const float* edges     = (const float*)d_in[1];
    const float* gvec      = (const float*)d_in[2];
    const int*   senders   = (const int*)  d_in[3];
    const int*   receivers = (const int*)  d_in[4];

    const float* ne_Win  = (const float*)d_in[5];
    const float* ne_bin  = (const float*)d_in[6];
    const float* ne_Wh   = (const float*)d_in[7];
    const float* ne_bh   = (const float*)d_in[8];
    const float* ne_Wout = (const float*)d_in[9];
    const float* ne_bout = (const float*)d_in[10];

    const float* ed_Win  = (const float*)d_in[11];
    const float* ed_bin  = (const float*)d_in[12];
    const float* ed_Wh   = (const float*)d_in[13];
    const float* ed_bh   = (const float*)d_in[14];
    const float* ed_Wout = (const float*)d_in[15];
    const float* ed_bout = (const float*)d_in[16];

    const float* pe_Win  = (const float*)d_in[17];
    const float* pe_bin  = (const float*)d_in[18];
    const float* pe_Wh   = (const float*)d_in[19];
    const float* pe_bh   = (const float*)d_in[20];
    const float* pe_Wout = (const float*)d_in[21];
    const float* pe_bout = (const float*)d_in[22];
    const float* pe_lng  = (const float*)d_in[23];
    const float* pe_lnb  = (const float*)d_in[24];

    const float* pv_Win  = (const float*)d_in[25];
    const float* pv_bin  = (const float*)d_in[26];
    const float* pv_Wh   = (const float*)d_in[27];
    const float* pv_bh   = (const float*)d_in[28];
    const float* pv_Wout = (const float*)d_in[29];
    const float* pv_bout = (const float*)d_in[30];
    const float* pv_lng  = (const float*)d_in[31];
    const float* pv_lnb  = (const float*)d_in[32];

    const float* de_Win  = (const float*)d_in[33];
    const float* de_bin  = (const float*)d_in[34];
    const float* de_Wh   = (const float*)d_in[35];
    const float* de_bh   = (const float*)d_in[36];
    const float* de_Wout = (const float*)d_in[37];
    const float* de_bout = (const float*)d_in[38];

    // workspace: ve | ee | agg (4 MB each) | packed bf16 weights
    float* ve  = (float*)d_ws;
    float* ee  = ve + (size_t)1048576;
    float* agg = ee + (size_t)1048576;
    u32* Wne = (u32*)(agg + (size_t)1048576);
    u32* Wed = Wne + 17152;
    u32* Wpe = Wed + 17152;
    u32* Wpv = Wpe + 17664;
    u32* Wde = Wpv + 17664;

    const dim3 blk(256);

    pack_kernel<<<70, blk, 0, stream>>>(ne_Win, ne_Wh, ne_Wout, Wne,  7, 16, 32);
    pack_kernel<<<70, blk, 0, stream>>>(ed_Win, ed_Wh, ed_Wout, Wed,  5, 16, 32);
    pack_kernel<<<70, blk, 0, stream>>>(pe_Win, pe_Wh, pe_Wout, Wpe, 49, 16, 64);
    pack_kernel<<<70, blk, 0, stream>>>(pv_Win, pv_Wh, pv_Wout, Wpv, 33, 16, 64);
    pack_kernel<<<70, blk, 0, stream>>>(de_Win, de_Wh, de_Wout, Wde, 16,  3, 32);

    encode_kernel<<<2048, blk, 0, stream>>>(nodes, edges, gvec, senders, receivers,
        Wne, ne_bin, ne_bh, ne_bout,
        Wed, ed_bin, ed_bh, ed_bout, ve, ee);

    for (int step = 0; step < 2; ++step) {
        hipMemsetAsync(agg, 0, (size_t)BB * NN * 16 * sizeof(float), stream);
        edge_update_kernel<<<1024, blk, 0, stream>>>(gvec, senders, receivers,
            ve, ee, agg, Wpe, pe_bin, pe_bh, pe_bout, pe_lng, pe_lnb);
        node_update_kernel<<<1024, blk, 0, stream>>>(gvec, agg, ve,
            Wpv, pv_bin, pv_bh, pv_bout, pv_lng, pv_lnb);
    }

    decode_kernel<<<1024, blk, 0, stream>>>(ve,
        Wde, de_bin, de_bh, de_bout, (float*)d_out);
}